// Round 1
// baseline (2719.495 us; speedup 1.0000x reference)
//
#include <hip/hip_runtime.h>
#include <math.h>

#define B_ 8
#define T_ 1024
#define F_ 1024
#define H_ 16
#define D_ 64

// ---------------------------------------------------------------------------
// Kernel 1: fused QKV projection.
// X [8192,1024] @ W^T (W [3072,1024]) + bias -> scatter into q/k/v [B,H,T,D]
// 64x64 tile, BK=16, 256 threads, 4x4 per thread.
// ---------------------------------------------------------------------------
__global__ __launch_bounds__(256) void qkv_proj_kernel(
    const float* __restrict__ X,
    const float* __restrict__ W,
    const float* __restrict__ bias,
    float* __restrict__ qw, float* __restrict__ kw, float* __restrict__ vw)
{
    const int K = F_;
    int n0 = blockIdx.x * 64;
    int m0 = blockIdx.y * 64;
    __shared__ float As[16][68];
    __shared__ float Bs[16][68];
    int tid = threadIdx.x;
    int tx = tid & 15, ty = tid >> 4;
    int lr = tid >> 2;          // 0..63 tile row
    int lk = (tid & 3) << 2;    // 0,4,8,12 within K-chunk
    const float* Aptr = X + (size_t)(m0 + lr) * K + lk;
    const float* Wptr = W + (size_t)(n0 + lr) * K + lk;
    float acc[4][4] = {};
    for (int kc = 0; kc < K; kc += 16) {
        float4 av = *(const float4*)(Aptr + kc);
        float4 wv = *(const float4*)(Wptr + kc);
        __syncthreads();
        As[lk+0][lr] = av.x; As[lk+1][lr] = av.y; As[lk+2][lr] = av.z; As[lk+3][lr] = av.w;
        Bs[lk+0][lr] = wv.x; Bs[lk+1][lr] = wv.y; Bs[lk+2][lr] = wv.z; Bs[lk+3][lr] = wv.w;
        __syncthreads();
        #pragma unroll
        for (int kk = 0; kk < 16; kk++) {
            float4 a = *(const float4*)&As[kk][ty*4];
            float4 b = *(const float4*)&Bs[kk][tx*4];
            acc[0][0] += a.x*b.x; acc[0][1] += a.x*b.y; acc[0][2] += a.x*b.z; acc[0][3] += a.x*b.w;
            acc[1][0] += a.y*b.x; acc[1][1] += a.y*b.y; acc[1][2] += a.y*b.z; acc[1][3] += a.y*b.w;
            acc[2][0] += a.z*b.x; acc[2][1] += a.z*b.y; acc[2][2] += a.z*b.z; acc[2][3] += a.z*b.w;
            acc[3][0] += a.w*b.x; acc[3][1] += a.w*b.y; acc[3][2] += a.w*b.z; acc[3][3] += a.w*b.w;
        }
    }
    // epilogue: n-tile (64 wide, 64-aligned) lies entirely in one {q,k,v} chunk
    // and one head (chunks 1024-aligned, heads 64-aligned).
    int which = n0 >> 10;
    int h = (n0 & 1023) >> 6;
    float* dst = (which == 0) ? qw : (which == 1) ? kw : vw;
    float b0 = bias[n0 + tx*4 + 0];
    float b1 = bias[n0 + tx*4 + 1];
    float b2 = bias[n0 + tx*4 + 2];
    float b3 = bias[n0 + tx*4 + 3];
    #pragma unroll
    for (int i = 0; i < 4; i++) {
        int m = m0 + ty*4 + i;
        int b = m >> 10, t = m & 1023;
        float4 o;
        o.x = acc[i][0] + b0;
        o.y = acc[i][1] + b1;
        o.z = acc[i][2] + b2;
        o.w = acc[i][3] + b3;
        *(float4*)(dst + (size_t)((b*H_ + h)*T_ + t)*D_ + tx*4) = o;
    }
}

// ---------------------------------------------------------------------------
// Kernel 2: scores + mask + softmax, fused per (b,h,8 q-rows).
// Writes alpha directly into d_out's alpha region. Scores kept in LDS.
// ---------------------------------------------------------------------------
__global__ __launch_bounds__(256) void attn_kernel(
    const float* __restrict__ qw, const float* __restrict__ kw,
    const int* __restrict__ mask, float* __restrict__ alpha)
{
    int b = blockIdx.z, h = blockIdx.y;
    int q0 = blockIdx.x * 8;
    __shared__ float Qs[8][64];
    __shared__ float Ks[64][68];
    __shared__ float S[8][1024];
    int tid = threadIdx.x;
    const float* qbase = qw + (size_t)((b*H_ + h)*T_ + q0) * D_;
    if (tid < 128) {
        int idx = tid * 4;
        int r = idx >> 6, d = idx & 63;
        *(float4*)&Qs[r][d] = *(const float4*)(qbase + r*D_ + d);
    }
    const float* kbase = kw + (size_t)((b*H_ + h)*T_) * D_;
    int qi = tid >> 5;          // 0..7
    int kb = (tid & 31) * 2;    // 0..62
    for (int kt = 0; kt < 16; kt++) {
        __syncthreads();   // protects Ks reuse (and Qs on first iter)
        #pragma unroll
        for (int i = 0; i < 4; i++) {
            int idx = (tid + i*256) * 4;
            int r = idx >> 6, d = idx & 63;
            *(float4*)&Ks[r][d] = *(const float4*)(kbase + (size_t)(kt*64 + r)*D_ + d);
        }
        __syncthreads();
        float acc0 = 0.f, acc1 = 0.f;
        const float4* q4  = (const float4*)&Qs[qi][0];
        const float4* k40 = (const float4*)&Ks[kb][0];
        const float4* k41 = (const float4*)&Ks[kb+1][0];
        #pragma unroll
        for (int d4 = 0; d4 < 16; d4++) {
            float4 qv = q4[d4];
            float4 k0 = k40[d4];
            float4 k1 = k41[d4];
            acc0 += qv.x*k0.x + qv.y*k0.y + qv.z*k0.z + qv.w*k0.w;
            acc1 += qv.x*k1.x + qv.y*k1.y + qv.z*k1.z + qv.w*k1.w;
        }
        *(float2*)&S[qi][kt*64 + kb] = make_float2(acc0, acc1);
    }
    __syncthreads();
    // softmax: 32 threads per row, strided by 32 (bank-conflict-free)
    int row = tid >> 5;
    int tx2 = tid & 31;
    const int* mrow = mask + b * T_;
    float mx = -INFINITY;
    #pragma unroll
    for (int i = 0; i < 32; i++) {
        int k = tx2 + i*32;
        float sv = mrow[k] ? -INFINITY : S[row][k] * 0.125f;
        S[row][k] = sv;
        mx = fmaxf(mx, sv);
    }
    #pragma unroll
    for (int off = 16; off; off >>= 1)
        mx = fmaxf(mx, __shfl_xor(mx, off, 64));
    float sum = 0.f;
    #pragma unroll
    for (int i = 0; i < 32; i++) {
        int k = tx2 + i*32;
        float e = __expf(S[row][k] - mx);
        S[row][k] = e;
        sum += e;
    }
    #pragma unroll
    for (int off = 16; off; off >>= 1)
        sum += __shfl_xor(sum, off, 64);
    float inv = 1.0f / sum;
    float* arow = alpha + (size_t)((b*H_ + h)*T_ + q0 + row) * T_;
    #pragma unroll
    for (int i = 0; i < 32; i++) {
        int k = tx2 + i*32;
        arow[k] = S[row][k] * inv;
    }
}

// ---------------------------------------------------------------------------
// Kernel 3: att = alpha @ V per (b,h). C tile [64 q][64 d] = full D.
// Writes att in [B,T,F] layout for the output projection.
// ---------------------------------------------------------------------------
__global__ __launch_bounds__(256) void attn_v_kernel(
    const float* __restrict__ alpha, const float* __restrict__ vw,
    float* __restrict__ att)
{
    int q0 = blockIdx.x * 64;
    int h = blockIdx.y, b = blockIdx.z;
    __shared__ float As[16][68];
    __shared__ float Vs[16][68];
    int tid = threadIdx.x;
    int tx = tid & 15, ty = tid >> 4;
    int lr = tid >> 2;
    int lk = (tid & 3) << 2;
    const float* abase = alpha + (size_t)((b*H_ + h)*T_ + q0) * T_;
    const float* vbase = vw + (size_t)((b*H_ + h)*T_) * D_;
    float acc[4][4] = {};
    int vr = tid >> 4;          // 0..15
    int vd = (tid & 15) * 4;    // 0..60
    for (int kc = 0; kc < T_; kc += 16) {
        float4 av = *(const float4*)(abase + (size_t)lr * T_ + kc + lk);
        float4 vv = *(const float4*)(vbase + (size_t)(kc + vr) * D_ + vd);
        __syncthreads();
        As[lk+0][lr] = av.x; As[lk+1][lr] = av.y; As[lk+2][lr] = av.z; As[lk+3][lr] = av.w;
        *(float4*)&Vs[vr][vd] = vv;
        __syncthreads();
        #pragma unroll
        for (int kk = 0; kk < 16; kk++) {
            float4 a = *(const float4*)&As[kk][ty*4];
            float4 v = *(const float4*)&Vs[kk][tx*4];
            acc[0][0] += a.x*v.x; acc[0][1] += a.x*v.y; acc[0][2] += a.x*v.z; acc[0][3] += a.x*v.w;
            acc[1][0] += a.y*v.x; acc[1][1] += a.y*v.y; acc[1][2] += a.y*v.z; acc[1][3] += a.y*v.w;
            acc[2][0] += a.z*v.x; acc[2][1] += a.z*v.y; acc[2][2] += a.z*v.z; acc[2][3] += a.z*v.w;
            acc[3][0] += a.w*v.x; acc[3][1] += a.w*v.y; acc[3][2] += a.w*v.z; acc[3][3] += a.w*v.w;
        }
    }
    #pragma unroll
    for (int i = 0; i < 4; i++) {
        int t = q0 + ty*4 + i;
        *(float4*)(att + (size_t)(b*T_ + t) * F_ + h*D_ + tx*4) =
            make_float4(acc[i][0], acc[i][1], acc[i][2], acc[i][3]);
    }
}

// ---------------------------------------------------------------------------
// Kernel 4: out = att [8192,1024] @ out_proj_w^T + bias -> d_out[0 : 8.39M]
// ---------------------------------------------------------------------------
__global__ __launch_bounds__(256) void out_proj_kernel(
    const float* __restrict__ A,
    const float* __restrict__ W,
    const float* __restrict__ bias,
    float* __restrict__ out)
{
    const int K = F_;
    int n0 = blockIdx.x * 64;
    int m0 = blockIdx.y * 64;
    __shared__ float As[16][68];
    __shared__ float Bs[16][68];
    int tid = threadIdx.x;
    int tx = tid & 15, ty = tid >> 4;
    int lr = tid >> 2;
    int lk = (tid & 3) << 2;
    const float* Aptr = A + (size_t)(m0 + lr) * K + lk;
    const float* Wptr = W + (size_t)(n0 + lr) * K + lk;
    float acc[4][4] = {};
    for (int kc = 0; kc < K; kc += 16) {
        float4 av = *(const float4*)(Aptr + kc);
        float4 wv = *(const float4*)(Wptr + kc);
        __syncthreads();
        As[lk+0][lr] = av.x; As[lk+1][lr] = av.y; As[lk+2][lr] = av.z; As[lk+3][lr] = av.w;
        Bs[lk+0][lr] = wv.x; Bs[lk+1][lr] = wv.y; Bs[lk+2][lr] = wv.z; Bs[lk+3][lr] = wv.w;
        __syncthreads();
        #pragma unroll
        for (int kk = 0; kk < 16; kk++) {
            float4 a = *(const float4*)&As[kk][ty*4];
            float4 b = *(const float4*)&Bs[kk][tx*4];
            acc[0][0] += a.x*b.x; acc[0][1] += a.x*b.y; acc[0][2] += a.x*b.z; acc[0][3] += a.x*b.w;
            acc[1][0] += a.y*b.x; acc[1][1] += a.y*b.y; acc[1][2] += a.y*b.z; acc[1][3] += a.y*b.w;
            acc[2][0] += a.z*b.x; acc[2][1] += a.z*b.y; acc[2][2] += a.z*b.z; acc[2][3] += a.z*b.w;
            acc[3][0] += a.w*b.x; acc[3][1] += a.w*b.y; acc[3][2] += a.w*b.z; acc[3][3] += a.w*b.w;
        }
    }
    float b0 = bias[n0 + tx*4 + 0];
    float b1 = bias[n0 + tx*4 + 1];
    float b2 = bias[n0 + tx*4 + 2];
    float b3 = bias[n0 + tx*4 + 3];
    #pragma unroll
    for (int i = 0; i < 4; i++) {
        int m = m0 + ty*4 + i;
        float4 o;
        o.x = acc[i][0] + b0;
        o.y = acc[i][1] + b1;
        o.z = acc[i][2] + b2;
        o.w = acc[i][3] + b3;
        *(float4*)(out + (size_t)m * F_ + n0 + tx*4) = o;
    }
}

extern "C" void kernel_launch(void* const* d_in, const int* in_sizes, int n_in,
                              void* d_out, int out_size, void* d_ws, size_t ws_size,
                              hipStream_t stream)
{
    const float* qkv   = (const float*)d_in[0];
    const int*   mask  = (const int*)d_in[1];
    const float* in_w  = (const float*)d_in[2];
    const float* in_b  = (const float*)d_in[3];
    const float* out_w = (const float*)d_in[4];
    const float* out_b = (const float*)d_in[5];
    float* out = (float*)d_out;
    const size_t NE = (size_t)B_ * T_ * F_;   // 8388608
    float* alpha = out + NE;                  // alpha region of d_out
    float* ws  = (float*)d_ws;
    float* qw  = ws;
    float* kw  = ws + NE;
    float* vw  = ws + 2*NE;
    float* att = ws + 3*NE;

    qkv_proj_kernel<<<dim3(48, 128), 256, 0, stream>>>(qkv, in_w, in_b, qw, kw, vw);
    attn_kernel<<<dim3(128, 16, 8), 256, 0, stream>>>(qw, kw, mask, alpha);
    attn_v_kernel<<<dim3(16, 16, 8), 256, 0, stream>>>(alpha, vw, att);
    out_proj_kernel<<<dim3(16, 128), 256, 0, stream>>>(att, out_w, out_b, out);
}

// Round 2
// 963.580 us; speedup vs baseline: 2.8223x; 2.8223x over previous
//
#include <hip/hip_runtime.h>
#include <math.h>

#define B_ 8
#define T_ 1024
#define F_ 1024
#define H_ 16
#define D_ 64

typedef __bf16 bf16x8 __attribute__((ext_vector_type(8)));
typedef float f32x4 __attribute__((ext_vector_type(4)));
typedef unsigned short u16x8 __attribute__((ext_vector_type(8)));

__device__ __forceinline__ unsigned short f2bf(float f) {
    union { float f; unsigned u; } v; v.f = f;
    unsigned r = v.u + 0x7fffu + ((v.u >> 16) & 1u);
    return (unsigned short)(r >> 16);
}

__device__ __forceinline__ void gld16(const void* g, void* l) {
    __builtin_amdgcn_global_load_lds(
        (const __attribute__((address_space(1))) void*)g,
        (__attribute__((address_space(3))) void*)l, 16, 0, 0);
}

// f(row) for 4-chunk (64B) rows: involution on chunk index, uses row&15 only
__device__ __forceinline__ int swz4(int row15) {
    return (row15 ^ (row15 >> 2)) & 3;
}

// ---------------------------------------------------------------------------
// fp32 -> bf16 conversion, 8 elems/thread
// ---------------------------------------------------------------------------
__global__ __launch_bounds__(256) void cvt_f32_bf16(
    const float* __restrict__ in, unsigned short* __restrict__ out, int n8)
{
    int i = blockIdx.x * 256 + threadIdx.x;
    if (i >= n8) return;
    const float4* p = (const float4*)in + (size_t)i * 2;
    float4 x = p[0], y = p[1];
    u16x8 o;
    o[0] = f2bf(x.x); o[1] = f2bf(x.y); o[2] = f2bf(x.z); o[3] = f2bf(x.w);
    o[4] = f2bf(y.x); o[5] = f2bf(y.y); o[6] = f2bf(y.z); o[7] = f2bf(y.w);
    ((u16x8*)out)[i] = o;
}

// ---------------------------------------------------------------------------
// QKV projection: Xb[8192,1024]bf16 @ Wb^T (Wb[3072,1024]bf16) + bias(fp32)
// -> qb,kb bf16 [B,H,T,D]; vb bf16 [B,H,D,T] (transposed for PV GEMM)
// 128x128 tile, BK=32, 4 waves each 64x64, global_load_lds w=16, XOR swizzle.
// ---------------------------------------------------------------------------
__global__ __launch_bounds__(256) void qkv_gemm(
    const unsigned short* __restrict__ A,
    const unsigned short* __restrict__ Bw,
    const float* __restrict__ bias,
    unsigned short* __restrict__ qb,
    unsigned short* __restrict__ kb,
    unsigned short* __restrict__ vb)
{
    __shared__ __align__(16) unsigned short As[128 * 32];
    __shared__ __align__(16) unsigned short Bs[128 * 32];
    const int K = 1024;
    int tid = threadIdx.x;
    int lane = tid & 63, wave = tid >> 6;
    int wr = wave >> 1, wc = wave & 1;
    int m0 = blockIdx.y * 128, n0 = blockIdx.x * 128;
    int col = lane & 15, quad = lane >> 4;
    int sw = swz4(col);
    // staging lane decomposition: 16 rows x 4 chunks(16B) per wave-instr
    int rl = lane >> 2;
    int lc = (lane & 3) ^ swz4(rl);

    f32x4 acc[4][4] = {};
    for (int kc = 0; kc < K; kc += 32) {
        __syncthreads();
        #pragma unroll
        for (int l = 0; l < 2; l++) {
            int ia = wave * 2 + l;
            gld16(A  + (size_t)(m0 + ia * 16 + rl) * K + kc + lc * 8, &As[ia * 512]);
            gld16(Bw + (size_t)(n0 + ia * 16 + rl) * K + kc + lc * 8, &Bs[ia * 512]);
        }
        __syncthreads();
        bf16x8 af[4], bg[4];
        #pragma unroll
        for (int mt = 0; mt < 4; mt++)
            af[mt] = *(const bf16x8*)&As[(wr * 64 + mt * 16 + col) * 32 + ((quad ^ sw)) * 8];
        #pragma unroll
        for (int nt = 0; nt < 4; nt++)
            bg[nt] = *(const bf16x8*)&Bs[(wc * 64 + nt * 16 + col) * 32 + ((quad ^ sw)) * 8];
        #pragma unroll
        for (int mt = 0; mt < 4; mt++)
            #pragma unroll
            for (int nt = 0; nt < 4; nt++)
                acc[mt][nt] = __builtin_amdgcn_mfma_f32_16x16x32_bf16(
                    af[mt], bg[nt], acc[mt][nt], 0, 0, 0);
    }
    // epilogue: n-tile (128-wide) never crosses the q/k/v 1024-boundaries
    int which = n0 >> 10;
    #pragma unroll
    for (int nt = 0; nt < 4; nt++) {
        int n = n0 + wc * 64 + nt * 16 + col;
        int hn = (n & 1023) >> 6, d = n & 63;
        float bn = bias[n];
        #pragma unroll
        for (int mt = 0; mt < 4; mt++) {
            #pragma unroll
            for (int r = 0; r < 4; r++) {
                int m = m0 + wr * 64 + mt * 16 + quad * 4 + r;
                int bb = m >> 10, t = m & 1023;
                unsigned short bf = f2bf(acc[mt][nt][r] + bn);
                if (which == 0)
                    qb[(size_t)((bb * H_ + hn) * T_ + t) * D_ + d] = bf;
                else if (which == 1)
                    kb[(size_t)((bb * H_ + hn) * T_ + t) * D_ + d] = bf;
                else
                    vb[(size_t)((bb * H_ + hn) * D_ + d) * T_ + t] = bf;
            }
        }
    }
}

// ---------------------------------------------------------------------------
// Scores + mask + softmax. Block = (b,h,16 q-rows), 4 waves each own 256 keys.
// S held in 64 acc VGPRs per lane; alpha fp32 written straight to d_out.
// ---------------------------------------------------------------------------
__global__ __launch_bounds__(256) void attn_kernel(
    const unsigned short* __restrict__ qb,
    const unsigned short* __restrict__ kb,
    const int* __restrict__ mask,
    float* __restrict__ alpha)
{
    __shared__ __align__(16) unsigned short Qs[16 * 72];   // padded rows (144B)
    __shared__ __align__(16) unsigned short Ks[4][64 * 64]; // per-wave 64 keys x 64d
    __shared__ float redmax[4][16];
    __shared__ float redsum[4][16];
    int b = blockIdx.z, h = blockIdx.y, q0 = blockIdx.x * 16;
    int tid = threadIdx.x, lane = tid & 63, wave = tid >> 6;
    int col = lane & 15, quad = lane >> 4;
    const unsigned short* qbase = qb + ((size_t)(b * H_ + h) * T_ + q0) * D_;
    const unsigned short* kbase = kb + ((size_t)(b * H_ + h) * T_) * D_;

    if (tid < 128) {  // stage Q: 16 rows x 64 bf16
        int r = tid >> 3, c = tid & 7;
        *(u16x8*)&Qs[r * 72 + c * 8] = *(const u16x8*)&qbase[r * 64 + c * 8];
    }
    int krl = lane >> 3;              // 8 rows per wave-instr
    int klc = (lane & 7) ^ krl;       // logical chunk (8 chunks of 16B per 128B row)
    int sw8 = col & 7;
    f32x4 acc[4][4] = {};
    bf16x8 aq0, aq1;
    for (int it = 0; it < 4; it++) {
        int kr0 = wave * 256 + it * 64;
        #pragma unroll
        for (int j = 0; j < 8; j++)
            gld16(kbase + (size_t)(kr0 + j * 8 + krl) * 64 + klc * 8, &Ks[wave][j * 512]);
        __syncthreads();
        if (it == 0) {
            aq0 = *(const bf16x8*)&Qs[col * 72 + quad * 8];
            aq1 = *(const bf16x8*)&Qs[col * 72 + 32 + quad * 8];
        }
        #pragma unroll
        for (int ct = 0; ct < 4; ct++) {
            int r = ct * 16 + col;
            const unsigned short* kp = &Ks[wave][r * 64];
            bf16x8 b0 = *(const bf16x8*)&kp[(quad ^ sw8) * 8];
            bf16x8 b1 = *(const bf16x8*)&kp[((4 + quad) ^ sw8) * 8];
            acc[it][ct] = __builtin_amdgcn_mfma_f32_16x16x32_bf16(aq0, b0, acc[it][ct], 0, 0, 0);
            acc[it][ct] = __builtin_amdgcn_mfma_f32_16x16x32_bf16(aq1, b1, acc[it][ct], 0, 0, 0);
        }
        __syncthreads();
    }
    // scale + mask + row max (rows = quad*4+r, this wave's 256-key strip)
    const int* mrow = mask + b * T_;
    float mx[4] = {-INFINITY, -INFINITY, -INFINITY, -INFINITY};
    #pragma unroll
    for (int it = 0; it < 4; it++)
        #pragma unroll
        for (int ct = 0; ct < 4; ct++) {
            int k = wave * 256 + it * 64 + ct * 16 + col;
            bool m = mrow[k] != 0;
            #pragma unroll
            for (int r = 0; r < 4; r++) {
                float v = m ? -INFINITY : acc[it][ct][r] * 0.125f;
                acc[it][ct][r] = v;
                mx[r] = fmaxf(mx[r], v);
            }
        }
    #pragma unroll
    for (int r = 0; r < 4; r++) {
        mx[r] = fmaxf(mx[r], __shfl_xor(mx[r], 1, 64));
        mx[r] = fmaxf(mx[r], __shfl_xor(mx[r], 2, 64));
        mx[r] = fmaxf(mx[r], __shfl_xor(mx[r], 4, 64));
        mx[r] = fmaxf(mx[r], __shfl_xor(mx[r], 8, 64));
    }
    if (col == 0)
        #pragma unroll
        for (int r = 0; r < 4; r++) redmax[wave][quad * 4 + r] = mx[r];
    __syncthreads();
    float gm[4];
    #pragma unroll
    for (int r = 0; r < 4; r++) {
        int row = quad * 4 + r;
        gm[r] = fmaxf(fmaxf(redmax[0][row], redmax[1][row]),
                      fmaxf(redmax[2][row], redmax[3][row]));
    }
    float sm[4] = {0.f, 0.f, 0.f, 0.f};
    #pragma unroll
    for (int it = 0; it < 4; it++)
        #pragma unroll
        for (int ct = 0; ct < 4; ct++)
            #pragma unroll
            for (int r = 0; r < 4; r++) {
                float e = __expf(acc[it][ct][r] - gm[r]);
                acc[it][ct][r] = e;
                sm[r] += e;
            }
    #pragma unroll
    for (int r = 0; r < 4; r++) {
        sm[r] += __shfl_xor(sm[r], 1, 64);
        sm[r] += __shfl_xor(sm[r], 2, 64);
        sm[r] += __shfl_xor(sm[r], 4, 64);
        sm[r] += __shfl_xor(sm[r], 8, 64);
    }
    if (col == 0)
        #pragma unroll
        for (int r = 0; r < 4; r++) redsum[wave][quad * 4 + r] = sm[r];
    __syncthreads();
    float inv[4];
    #pragma unroll
    for (int r = 0; r < 4; r++) {
        int row = quad * 4 + r;
        inv[r] = 1.0f / (redsum[0][row] + redsum[1][row] + redsum[2][row] + redsum[3][row]);
    }
    float* abase = alpha + ((size_t)(b * H_ + h) * T_ + q0) * T_;
    #pragma unroll
    for (int it = 0; it < 4; it++)
        #pragma unroll
        for (int ct = 0; ct < 4; ct++) {
            int k = wave * 256 + it * 64 + ct * 16 + col;
            #pragma unroll
            for (int r = 0; r < 4; r++)
                abase[(size_t)(quad * 4 + r) * T_ + k] = acc[it][ct][r] * inv[r];
        }
}

// ---------------------------------------------------------------------------
// att = alpha @ V.  Block = (b,h,64 q) x full D=64. alpha fp32 -> bf16 via LDS.
// V is [B,H,D,T] so both operands are K(t)-contiguous. att written bf16 [B,T,F].
// ---------------------------------------------------------------------------
__global__ __launch_bounds__(256) void attn_v_kernel(
    const float* __restrict__ alpha,
    const unsigned short* __restrict__ vb,
    unsigned short* __restrict__ attb)
{
    __shared__ __align__(16) unsigned short As[64 * 72]; // padded rows (144B)
    __shared__ __align__(16) unsigned short Vs[64 * 32];
    int b = blockIdx.z, h = blockIdx.y, q0 = blockIdx.x * 64;
    int tid = threadIdx.x, lane = tid & 63, wave = tid >> 6;
    int col = lane & 15, quad = lane >> 4;
    int swv = swz4(col);
    const float* abase = alpha + ((size_t)(b * H_ + h) * T_ + q0) * T_;
    const unsigned short* vbase = vb + (size_t)(b * H_ + h) * D_ * T_;
    int ar = tid >> 2, acg = tid & 3;         // A stage: q-row, 8-col group
    int vrl = lane >> 2;
    int vlc = (lane & 3) ^ swz4(vrl);
    f32x4 acc[4] = {};
    for (int kc = 0; kc < T_; kc += 32) {
        __syncthreads();
        gld16(vbase + (size_t)(wave * 16 + vrl) * T_ + kc + vlc * 8, &Vs[wave * 512]);
        float4 x = *(const float4*)&abase[(size_t)ar * T_ + kc + acg * 8];
        float4 y = *(const float4*)&abase[(size_t)ar * T_ + kc + acg * 8 + 4];
        u16x8 p;
        p[0] = f2bf(x.x); p[1] = f2bf(x.y); p[2] = f2bf(x.z); p[3] = f2bf(x.w);
        p[4] = f2bf(y.x); p[5] = f2bf(y.y); p[6] = f2bf(y.z); p[7] = f2bf(y.w);
        *(u16x8*)&As[ar * 72 + acg * 8] = p;
        __syncthreads();
        bf16x8 af = *(const bf16x8*)&As[(wave * 16 + col) * 72 + quad * 8];
        #pragma unroll
        for (int nt = 0; nt < 4; nt++) {
            int r = nt * 16 + col;
            bf16x8 bv = *(const bf16x8*)&Vs[r * 32 + ((quad ^ swv)) * 8];
            acc[nt] = __builtin_amdgcn_mfma_f32_16x16x32_bf16(af, bv, acc[nt], 0, 0, 0);
        }
    }
    #pragma unroll
    for (int nt = 0; nt < 4; nt++) {
        int d = nt * 16 + col;
        #pragma unroll
        for (int r = 0; r < 4; r++) {
            int t = q0 + wave * 16 + quad * 4 + r;
            attb[(size_t)(b * T_ + t) * F_ + h * D_ + d] = f2bf(acc[nt][r]);
        }
    }
}

// ---------------------------------------------------------------------------
// out = attb[8192,1024]bf16 @ Wob^T + bias -> fp32 d_out
// ---------------------------------------------------------------------------
__global__ __launch_bounds__(256) void out_gemm(
    const unsigned short* __restrict__ A,
    const unsigned short* __restrict__ Bw,
    const float* __restrict__ bias,
    float* __restrict__ out)
{
    __shared__ __align__(16) unsigned short As[128 * 32];
    __shared__ __align__(16) unsigned short Bs[128 * 32];
    const int K = 1024;
    int tid = threadIdx.x;
    int lane = tid & 63, wave = tid >> 6;
    int wr = wave >> 1, wc = wave & 1;
    int m0 = blockIdx.y * 128, n0 = blockIdx.x * 128;
    int col = lane & 15, quad = lane >> 4;
    int sw = swz4(col);
    int rl = lane >> 2;
    int lc = (lane & 3) ^ swz4(rl);
    f32x4 acc[4][4] = {};
    for (int kc = 0; kc < K; kc += 32) {
        __syncthreads();
        #pragma unroll
        for (int l = 0; l < 2; l++) {
            int ia = wave * 2 + l;
            gld16(A  + (size_t)(m0 + ia * 16 + rl) * K + kc + lc * 8, &As[ia * 512]);
            gld16(Bw + (size_t)(n0 + ia * 16 + rl) * K + kc + lc * 8, &Bs[ia * 512]);
        }
        __syncthreads();
        bf16x8 af[4], bg[4];
        #pragma unroll
        for (int mt = 0; mt < 4; mt++)
            af[mt] = *(const bf16x8*)&As[(wr * 64 + mt * 16 + col) * 32 + ((quad ^ sw)) * 8];
        #pragma unroll
        for (int nt = 0; nt < 4; nt++)
            bg[nt] = *(const bf16x8*)&Bs[(wc * 64 + nt * 16 + col) * 32 + ((quad ^ sw)) * 8];
        #pragma unroll
        for (int mt = 0; mt < 4; mt++)
            #pragma unroll
            for (int nt = 0; nt < 4; nt++)
                acc[mt][nt] = __builtin_amdgcn_mfma_f32_16x16x32_bf16(
                    af[mt], bg[nt], acc[mt][nt], 0, 0, 0);
    }
    #pragma unroll
    for (int nt = 0; nt < 4; nt++) {
        int n = n0 + wc * 64 + nt * 16 + col;
        float bn = bias[n];
        #pragma unroll
        for (int mt = 0; mt < 4; mt++) {
            #pragma unroll
            for (int r = 0; r < 4; r++) {
                int m = m0 + wr * 64 + mt * 16 + quad * 4 + r;
                out[(size_t)m * F_ + n] = acc[mt][nt][r] + bn;
            }
        }
    }
}

extern "C" void kernel_launch(void* const* d_in, const int* in_sizes, int n_in,
                              void* d_out, int out_size, void* d_ws, size_t ws_size,
                              hipStream_t stream)
{
    const float* qkv   = (const float*)d_in[0];
    const int*   mask  = (const int*)d_in[1];
    const float* in_w  = (const float*)d_in[2];
    const float* in_b  = (const float*)d_in[3];
    const float* out_w = (const float*)d_in[4];
    const float* out_b = (const float*)d_in[5];
    float* out = (float*)d_out;
    const size_t NE = (size_t)B_ * T_ * F_;       // 8388608
    float* alpha = out + NE;

    unsigned short* ws   = (unsigned short*)d_ws;
    unsigned short* Xb   = ws;                    // 8388608
    unsigned short* Wib  = Xb  + NE;              // 3145728
    unsigned short* Wob  = Wib + 3 * F_ * F_;     // 1048576
    unsigned short* qb2  = Wob + (size_t)F_ * F_; // 8388608
    unsigned short* kb2  = qb2 + NE;
    unsigned short* vb2  = kb2 + NE;
    unsigned short* attb = vb2 + NE;

    cvt_f32_bf16<<<dim3((int)(NE / 8 / 256)), 256, 0, stream>>>(qkv, Xb, (int)(NE / 8));
    cvt_f32_bf16<<<dim3(3 * F_ * F_ / 8 / 256), 256, 0, stream>>>(in_w, Wib, 3 * F_ * F_ / 8);
    cvt_f32_bf16<<<dim3(F_ * F_ / 8 / 256), 256, 0, stream>>>(out_w, Wob, F_ * F_ / 8);

    qkv_gemm<<<dim3(24, 64), 256, 0, stream>>>(Xb, Wib, in_b, qb2, kb2, vb2);
    attn_kernel<<<dim3(64, H_, B_), 256, 0, stream>>>(qb2, kb2, mask, alpha);
    attn_v_kernel<<<dim3(16, H_, B_), 256, 0, stream>>>(alpha, vb2, attb);
    out_gemm<<<dim3(8, 64), 256, 0, stream>>>(attb, Wob, out_b, out);
}